// Round 1
// baseline (7908.562 us; speedup 1.0000x reference)
//
#include <hip/hip_runtime.h>
#include <hip/hip_bf16.h>

typedef __bf16 bf16x8 __attribute__((ext_vector_type(8)));
typedef float f32x4 __attribute__((ext_vector_type(4)));

#define LSEQ 512
#define NB   256   // batch
#define NH   256   // hidden
#define KD   512   // NH + D (gate input g = [h, x])

// Converts initial h to bf16 and zeroes the barrier flag slots. Runs every
// launch (ws is re-poisoned to 0xAA before every timed call).
__global__ __launch_bounds__(256) void lstm_prep(const float* __restrict__ h0,
                                                 __bf16* __restrict__ hbf,
                                                 int* __restrict__ flags) {
  int i = blockIdx.x * 256 + threadIdx.x;
  hbf[i] = (__bf16)h0[i];
  if (blockIdx.x == 0) {
#pragma unroll
    for (int k = 0; k < 4; ++k) flags[threadIdx.x + k * 256] = 0;
  }
}

// Persistent LSTM kernel.
// Grid: blockIdx.x = row-group r (16 batch rows), blockIdx.y = col-block cb
// (16 hidden cols of each of the 4 gates). 256 blocks -> 1 per CU, all
// co-resident. Per-step sync is only among the 16 col-blocks of a row-group
// (flag slots in d_ws, device-scope atomics -> correct regardless of XCD
// placement; blockIdx.x-major linearization makes siblings share an XCD
// under round-robin dispatch for L2-local h exchange).
__global__ __launch_bounds__(256) void lstm_main(
    const float* __restrict__ x,
    const float* __restrict__ c0,
    const float* __restrict__ Wf, const float* __restrict__ bf_,
    const float* __restrict__ Wi, const float* __restrict__ bi_,
    const float* __restrict__ Wc, const float* __restrict__ bc_,
    const float* __restrict__ Wo, const float* __restrict__ bo_,
    float* __restrict__ out,
    __bf16* __restrict__ hbf,   // [2][NB][NH] double-buffered h (bf16)
    int* __restrict__ flags)    // 16 row-groups x 32-int stride
{
  const int r    = blockIdx.x;   // row-group 0..15
  const int cb   = blockIdx.y;   // col-block 0..15
  const int tid  = threadIdx.x;
  const int w    = tid >> 6;     // wave id == gate id (f, i, c~, o)
  const int lane = tid & 63;
  const int l15  = lane & 15;
  const int kg   = lane >> 4;    // k-group 0..3 within MFMA fragment

  __shared__ __align__(16) unsigned char Ash[16 * KD * 2];  // 16 rows x 512 k, bf16, XOR-swizzled
  __shared__ float zbuf[4][16][17];                         // gate pre-activations

  const int j0    = cb * 16;   // first hidden col of this block
  const int brow0 = r * 16;    // first batch row of this block

  // ---- B fragments: this wave's gate weights, resident in VGPRs (64/lane) ----
  const float* Wg = (w == 0) ? Wf : (w == 1) ? Wi : (w == 2) ? Wc : Wo;
  bf16x8 bfrag[16];
  {
    const float* wp = Wg + (size_t)(j0 + l15) * KD + kg * 8;
#pragma unroll
    for (int s = 0; s < 16; ++s) {
      float4 lo = *(const float4*)(wp + s * 32);
      float4 hi = *(const float4*)(wp + s * 32 + 4);
      bf16x8 v;
      v[0] = (__bf16)lo.x; v[1] = (__bf16)lo.y; v[2] = (__bf16)lo.z; v[3] = (__bf16)lo.w;
      v[4] = (__bf16)hi.x; v[5] = (__bf16)hi.y; v[6] = (__bf16)hi.z; v[7] = (__bf16)hi.w;
      bfrag[s] = v;
    }
  }

  // ---- per-thread epilogue mapping: (row, col) of the 16x16 output tile ----
  const int erow = tid >> 4, ecol = tid & 15;
  const int brow = brow0 + erow;
  const int jcol = j0 + ecol;
  const float biasf = bf_[jcol], biasi = bi_[jcol], biasc = bc_[jcol], biaso = bo_[jcol];
  float cst   = c0[brow * NH + jcol];  // cell state lives in a register
  float hlast = 0.f;

  int* slots = flags + r * 32;  // one cacheline of 16 slots per row-group

  for (int t = 0; t < LSEQ; ++t) {
    // 1) issue x_t loads BEFORE the barrier poll (independent of h) to hide
    //    HBM latency under the wait.
    const float* xp = x + ((size_t)t * NB * 256 + (size_t)brow * 256 + ecol * 16);
    float4 x0 = ((const float4*)xp)[0];
    float4 x1 = ((const float4*)xp)[1];
    float4 x2 = ((const float4*)xp)[2];
    float4 x3 = ((const float4*)xp)[3];

    // 2) wait until all 16 siblings published h_t (skip at t=0: prep wrote it)
    if (t > 0) {
      if (tid < 64) {
        const int target = t;
        while (1) {
          int v = __hip_atomic_load(&slots[lane & 15], __ATOMIC_RELAXED,
                                    __HIP_MEMORY_SCOPE_AGENT);
          if (__all(v >= target)) break;
          __builtin_amdgcn_s_sleep(1);
        }
      }
      __syncthreads();
      __builtin_amdgcn_fence(__ATOMIC_ACQUIRE, "agent");
    }

    // 3) stage A = [h_t | x_t] (16 rows x 512 k, bf16) into LDS, XOR-swizzled
    //    (byte ^= (row&7)<<4) so frag reads are bank-conflict-free.
    const __bf16* hc = hbf + (size_t)(t & 1) * (NB * NH);
    uint4 hv0 = *(const uint4*)(hc + brow * NH + ecol * 16);
    uint4 hv1 = *(const uint4*)(hc + brow * NH + ecol * 16 + 8);
    {
      int swz = (erow & 7) << 4;
      int base = erow * 1024;
      *(uint4*)&Ash[(base + (ecol * 16) * 2) ^ swz]           = hv0;
      *(uint4*)&Ash[(base + (ecol * 16 + 8) * 2) ^ swz]       = hv1;
      bf16x8 p0, p1;
      p0[0] = (__bf16)x0.x; p0[1] = (__bf16)x0.y; p0[2] = (__bf16)x0.z; p0[3] = (__bf16)x0.w;
      p0[4] = (__bf16)x1.x; p0[5] = (__bf16)x1.y; p0[6] = (__bf16)x1.z; p0[7] = (__bf16)x1.w;
      p1[0] = (__bf16)x2.x; p1[1] = (__bf16)x2.y; p1[2] = (__bf16)x2.z; p1[3] = (__bf16)x2.w;
      p1[4] = (__bf16)x3.x; p1[5] = (__bf16)x3.y; p1[6] = (__bf16)x3.z; p1[7] = (__bf16)x3.w;
      *(uint4*)&Ash[(base + (256 + ecol * 16) * 2) ^ swz]     = __builtin_bit_cast(uint4, p0);
      *(uint4*)&Ash[(base + (256 + ecol * 16 + 8) * 2) ^ swz] = __builtin_bit_cast(uint4, p1);
    }
    __syncthreads();

    // 4) 16 MFMAs: z[16x16] for this wave's gate, K=512
    f32x4 acc = {0.f, 0.f, 0.f, 0.f};
#pragma unroll
    for (int s = 0; s < 16; ++s) {
      int ab = ((l15 * 1024) + (s * 32 + kg * 8) * 2) ^ ((l15 & 7) << 4);
      bf16x8 a = *(const bf16x8*)&Ash[ab];
      acc = __builtin_amdgcn_mfma_f32_16x16x32_bf16(a, bfrag[s], acc, 0, 0, 0);
    }
    // C/D layout: col = lane&15, row = (lane>>4)*4 + reg  [m89-verified]
#pragma unroll
    for (int v4i = 0; v4i < 4; ++v4i) zbuf[w][kg * 4 + v4i][l15] = acc[v4i];
    __syncthreads();

    // 5) elementwise gate math; each thread owns one (row, col)
    float zf = zbuf[0][erow][ecol] + biasf;
    float zi = zbuf[1][erow][ecol] + biasi;
    float zc = zbuf[2][erow][ecol] + biasc;
    float zo = zbuf[3][erow][ecol] + biaso;
    float fg    = 1.f / (1.f + __expf(-zf));
    float ig    = 1.f / (1.f + __expf(-zi));
    float ccand = 1.f - 2.f / (__expf(2.f * zc) + 1.f);   // tanh
    float og    = 1.f / (1.f + __expf(-zo));
    cst   = fg * cst + ig * ccand;
    float tc = 1.f - 2.f / (__expf(2.f * cst) + 1.f);     // tanh
    hlast = og * tc;

    // publish h_{t+1} (bf16, critical path) first, then hAll (fp32)
    __bf16* hn = hbf + (size_t)((t + 1) & 1) * (NB * NH);
    hn[brow * NH + jcol] = (__bf16)hlast;
    out[(size_t)t * NB * NH + brow * NH + jcol] = hlast;

    // 6) arrive: all stores drained by the pre-barrier vmcnt(0), then leader
    //    release-stores this block's slot (no RMW contention).
    if (t < LSEQ - 1) {
      __syncthreads();
      if (tid == 0)
        __hip_atomic_store(&slots[cb], t + 1, __ATOMIC_RELEASE,
                           __HIP_MEMORY_SCOPE_AGENT);
    }
  }

  // finals: h_final, c_final
  out[(size_t)LSEQ * NB * NH + brow * NH + jcol]           = hlast;
  out[(size_t)LSEQ * NB * NH + NB * NH + brow * NH + jcol] = cst;
}

extern "C" void kernel_launch(void* const* d_in, const int* in_sizes, int n_in,
                              void* d_out, int out_size, void* d_ws, size_t ws_size,
                              hipStream_t stream) {
  const float* x  = (const float*)d_in[0];
  const float* h0 = (const float*)d_in[1];
  const float* c0 = (const float*)d_in[2];
  const float* Wf = (const float*)d_in[3];
  const float* bf = (const float*)d_in[4];
  const float* Wi = (const float*)d_in[5];
  const float* bi = (const float*)d_in[6];
  const float* Wc = (const float*)d_in[7];
  const float* bc = (const float*)d_in[8];
  const float* Wo = (const float*)d_in[9];
  const float* bo = (const float*)d_in[10];
  float* out = (float*)d_out;

  __bf16* hbf = (__bf16*)d_ws;                                   // 256 KB
  int* flags  = (int*)((char*)d_ws + (size_t)2 * NB * NH * 2);   // 4 KB

  lstm_prep<<<256, 256, 0, stream>>>(h0, hbf, flags);
  lstm_main<<<dim3(16, 16), 256, 0, stream>>>(x, c0, Wf, bf, Wi, bi, Wc, bc,
                                              Wo, bo, out, hbf, flags);
}

// Round 2
// 1735.502 us; speedup vs baseline: 4.5569x; 4.5569x over previous
//
#include <hip/hip_runtime.h>
#include <hip/hip_bf16.h>

typedef __bf16 bf16x8 __attribute__((ext_vector_type(8)));
typedef float f32x4 __attribute__((ext_vector_type(4)));

#define LSEQ 512
#define NB   256   // batch
#define NH   256   // hidden
#define KD   512   // NH + D (gate input g = [h, x])
#define HBUF_U32 (NB * NH / 2)   // one h buffer: bf16 pairs packed in u32

// Re-inits workspace every launch (ws is re-poisoned to 0xAA before every
// timed call): packs h0 into bf16-pair buffer 0 and zeroes arrival counters.
__global__ __launch_bounds__(256) void lstm_prep(const float* __restrict__ h0,
                                                 unsigned* __restrict__ hbuf,
                                                 int* __restrict__ cnt) {
  int g = blockIdx.x * 256 + threadIdx.x;   // grid 128 -> g in [0, 32768)
  float a = h0[2 * g], b = h0[2 * g + 1];
  unsigned pa = (unsigned)__builtin_bit_cast(unsigned short, (__bf16)a);
  unsigned pb = (unsigned)__builtin_bit_cast(unsigned short, (__bf16)b);
  hbuf[g] = pa | (pb << 16);
  if (g < 16 * LSEQ) cnt[g] = 0;
}

// Persistent LSTM. blockIdx.x = row-group r (16 batch rows), blockIdx.y =
// col-block cb (16 hidden cols of each of 4 gates). 256 blocks, 1/CU.
// Cross-block sync: fence-free. All h + counter traffic uses relaxed
// agent-scope atomics (global_load/store sc0 sc1 -> coherent at memory-side
// L3, no buffer_inv/buffer_wbl2). Arrival = per-wave atomicAdd after
// s_waitcnt vmcnt(0); departure = poll one dword until 64 arrivals.
__global__ __launch_bounds__(256) void lstm_main(
    const float* __restrict__ x,
    const float* __restrict__ c0,
    const float* __restrict__ Wf, const float* __restrict__ bf_,
    const float* __restrict__ Wi, const float* __restrict__ bi_,
    const float* __restrict__ Wc, const float* __restrict__ bc_,
    const float* __restrict__ Wo, const float* __restrict__ bo_,
    float* __restrict__ out,
    unsigned* __restrict__ hbuf,  // [2][NB][NH/2] bf16-pair h, double-buffered
    int* __restrict__ cnt)        // [16][LSEQ] arrival counters
{
  const int r    = blockIdx.x;   // row-group 0..15
  const int cb   = blockIdx.y;   // col-block 0..15
  const int tid  = threadIdx.x;
  const int w    = tid >> 6;     // wave id == gate id (f, i, c~, o)
  const int lane = tid & 63;
  const int l15  = lane & 15;
  const int kg   = lane >> 4;    // k-group 0..3 within MFMA fragment

  __shared__ __align__(16) unsigned char Ash[16 * KD * 2];  // 16 x 512 bf16, XOR-swizzled
  __shared__ float zbuf[4][16][17];                         // gate pre-activations

  const int j0    = cb * 16;
  const int brow0 = r * 16;

  // ---- B fragments: this wave's gate weights resident in VGPRs (64/lane) ----
  const float* Wg = (w == 0) ? Wf : (w == 1) ? Wi : (w == 2) ? Wc : Wo;
  bf16x8 bfrag[16];
  {
    const float* wp = Wg + (size_t)(j0 + l15) * KD + kg * 8;
#pragma unroll
    for (int s = 0; s < 16; ++s) {
      float4 lo = *(const float4*)(wp + s * 32);
      float4 hi = *(const float4*)(wp + s * 32 + 4);
      bf16x8 v;
      v[0] = (__bf16)lo.x; v[1] = (__bf16)lo.y; v[2] = (__bf16)lo.z; v[3] = (__bf16)lo.w;
      v[4] = (__bf16)hi.x; v[5] = (__bf16)hi.y; v[6] = (__bf16)hi.z; v[7] = (__bf16)hi.w;
      bfrag[s] = v;
    }
  }

  // ---- epilogue mapping: one thread per (row, col) of the 16x16 tile ----
  const int erow = tid >> 4, ecol = tid & 15;
  const int brow = brow0 + erow;
  const int jcol = j0 + ecol;
  const float biasf = bf_[jcol], biasi = bi_[jcol], biasc = bc_[jcol], biaso = bo_[jcol];
  float cst   = c0[brow * NH + jcol];
  float hlast = 0.f;

  int* mycnt = cnt + r * LSEQ;

  for (int t = 0; t < LSEQ; ++t) {
    // 1) x_t prefetch before the poll (independent of h) to hide HBM latency
    const float* xp = x + ((size_t)t * NB * 256 + (size_t)brow * 256 + ecol * 16);
    float4 x0 = ((const float4*)xp)[0];
    float4 x1 = ((const float4*)xp)[1];
    float4 x2 = ((const float4*)xp)[2];
    float4 x3 = ((const float4*)xp)[3];

    // 2) wait for all 64 producer waves of this row-group to finish step t-1
    if (t > 0) {
      while (__hip_atomic_load(&mycnt[t - 1], __ATOMIC_RELAXED,
                               __HIP_MEMORY_SCOPE_AGENT) < 64)
        __builtin_amdgcn_s_sleep(1);
      asm volatile("" ::: "memory");  // keep h loads below the poll
    }

    // 3) h_t loads: coherent (sc0 sc1) 8B atomic loads, bypass stale caches
    const unsigned long long* hp = (const unsigned long long*)(
        hbuf + (size_t)(t & 1) * HBUF_U32 + brow * (NH / 2) + ecol * 8);
    unsigned long long hq0 = __hip_atomic_load(&hp[0], __ATOMIC_RELAXED, __HIP_MEMORY_SCOPE_AGENT);
    unsigned long long hq1 = __hip_atomic_load(&hp[1], __ATOMIC_RELAXED, __HIP_MEMORY_SCOPE_AGENT);
    unsigned long long hq2 = __hip_atomic_load(&hp[2], __ATOMIC_RELAXED, __HIP_MEMORY_SCOPE_AGENT);
    unsigned long long hq3 = __hip_atomic_load(&hp[3], __ATOMIC_RELAXED, __HIP_MEMORY_SCOPE_AGENT);
    uint4 hv0, hv1;
    hv0.x = (unsigned)hq0; hv0.y = (unsigned)(hq0 >> 32);
    hv0.z = (unsigned)hq1; hv0.w = (unsigned)(hq1 >> 32);
    hv1.x = (unsigned)hq2; hv1.y = (unsigned)(hq2 >> 32);
    hv1.z = (unsigned)hq3; hv1.w = (unsigned)(hq3 >> 32);

    // 4) stage A = [h_t | x_t] into LDS, XOR-swizzled (byte ^= (row&7)<<4)
    {
      int swz  = (erow & 7) << 4;
      int base = erow * 1024;
      *(uint4*)&Ash[(base + (ecol * 16) * 2) ^ swz]     = hv0;
      *(uint4*)&Ash[(base + (ecol * 16 + 8) * 2) ^ swz] = hv1;
      bf16x8 p0, p1;
      p0[0] = (__bf16)x0.x; p0[1] = (__bf16)x0.y; p0[2] = (__bf16)x0.z; p0[3] = (__bf16)x0.w;
      p0[4] = (__bf16)x1.x; p0[5] = (__bf16)x1.y; p0[6] = (__bf16)x1.z; p0[7] = (__bf16)x1.w;
      p1[0] = (__bf16)x2.x; p1[1] = (__bf16)x2.y; p1[2] = (__bf16)x2.z; p1[3] = (__bf16)x2.w;
      p1[4] = (__bf16)x3.x; p1[5] = (__bf16)x3.y; p1[6] = (__bf16)x3.z; p1[7] = (__bf16)x3.w;
      *(uint4*)&Ash[(base + (256 + ecol * 16) * 2) ^ swz]     = __builtin_bit_cast(uint4, p0);
      *(uint4*)&Ash[(base + (256 + ecol * 16 + 8) * 2) ^ swz] = __builtin_bit_cast(uint4, p1);
    }
    __syncthreads();  // sync1: Ash staged

    // 5) 16 MFMAs: z[16x16] for this wave's gate, K=512
    f32x4 acc = {0.f, 0.f, 0.f, 0.f};
#pragma unroll
    for (int s = 0; s < 16; ++s) {
      int ab = ((l15 * 1024) + (s * 32 + kg * 8) * 2) ^ ((l15 & 7) << 4);
      bf16x8 a = *(const bf16x8*)&Ash[ab];
      acc = __builtin_amdgcn_mfma_f32_16x16x32_bf16(a, bfrag[s], acc, 0, 0, 0);
    }
    // C/D layout: col = lane&15, row = (lane>>4)*4 + reg  [m89-verified]
#pragma unroll
    for (int v4i = 0; v4i < 4; ++v4i) zbuf[w][kg * 4 + v4i][l15] = acc[v4i];
    __syncthreads();  // sync2: zbuf complete

    // 6) elementwise gate math; one thread per (row, col)
    float zf = zbuf[0][erow][ecol] + biasf;
    float zi = zbuf[1][erow][ecol] + biasi;
    float zc = zbuf[2][erow][ecol] + biasc;
    float zo = zbuf[3][erow][ecol] + biaso;
    float fg    = 1.f / (1.f + __expf(-zf));
    float ig    = 1.f / (1.f + __expf(-zi));
    float ccand = 1.f - 2.f / (__expf(2.f * zc) + 1.f);   // tanh
    float og    = 1.f / (1.f + __expf(-zo));
    cst   = fg * cst + ig * ccand;
    float tc = 1.f - 2.f / (__expf(2.f * cst) + 1.f);     // tanh
    hlast = og * tc;

    // 7) publish h_{t+1}: bf16 pairs, coherent store (no cache maintenance)
    unsigned mybits = (unsigned)__builtin_bit_cast(unsigned short, (__bf16)hlast);
    unsigned nbbits = __shfl_down(mybits, 1);
    if ((ecol & 1) == 0)
      __hip_atomic_store(&hbuf[(size_t)((t + 1) & 1) * HBUF_U32 + brow * (NH / 2) + (jcol >> 1)],
                         mybits | (nbbits << 16), __ATOMIC_RELAXED,
                         __HIP_MEMORY_SCOPE_AGENT);

    // 8) arrive: drain own stores, then fire-and-forget wave-level add.
    //    No __syncthreads here — pollers count 64 wave arrivals.
    if (t < LSEQ - 1) {
      asm volatile("s_waitcnt vmcnt(0)" ::: "memory");
      if (lane == 0)
        __hip_atomic_fetch_add(&mycnt[t], 1, __ATOMIC_RELAXED,
                               __HIP_MEMORY_SCOPE_AGENT);
    }

    // 9) hAll output (plain cached store; flushed at kernel end)
    out[(size_t)t * NB * NH + brow * NH + jcol] = hlast;
  }

  // finals: h_final, c_final
  out[(size_t)LSEQ * NB * NH + brow * NH + jcol]           = hlast;
  out[(size_t)LSEQ * NB * NH + NB * NH + brow * NH + jcol] = cst;
}

extern "C" void kernel_launch(void* const* d_in, const int* in_sizes, int n_in,
                              void* d_out, int out_size, void* d_ws, size_t ws_size,
                              hipStream_t stream) {
  const float* x  = (const float*)d_in[0];
  const float* h0 = (const float*)d_in[1];
  const float* c0 = (const float*)d_in[2];
  const float* Wf = (const float*)d_in[3];
  const float* bf = (const float*)d_in[4];
  const float* Wi = (const float*)d_in[5];
  const float* bi = (const float*)d_in[6];
  const float* Wc = (const float*)d_in[7];
  const float* bc = (const float*)d_in[8];
  const float* Wo = (const float*)d_in[9];
  const float* bo = (const float*)d_in[10];
  float* out = (float*)d_out;

  unsigned* hbuf = (unsigned*)d_ws;                                   // 256 KB
  int* cnt = (int*)((char*)d_ws + (size_t)2 * HBUF_U32 * 4);          // 32 KB

  lstm_prep<<<128, 256, 0, stream>>>(h0, hbuf, cnt);
  lstm_main<<<dim3(16, 16), 256, 0, stream>>>(x, c0, Wf, bf, Wi, bi, Wc, bc,
                                              Wo, bo, out, hbuf, cnt);
}

// Round 4
// 1194.787 us; speedup vs baseline: 6.6192x; 1.4526x over previous
//
#include <hip/hip_runtime.h>
#include <hip/hip_bf16.h>

typedef __bf16 bf16x8 __attribute__((ext_vector_type(8)));
typedef float f32x4 __attribute__((ext_vector_type(4)));

#define LSEQ 512
#define NB   256   // batch
#define NH   256   // hidden
#define KD   512   // NH + D (gate input g = [h, x])
#define HROW_U64 (NH / 2)            // u64 per h row (2 bf16 cols per u64)
#define HBUF_U64 (NB * HROW_U64)     // one parity buffer: 32768 u64 (256 KB)

// Re-inits h buffer 0 with tag-0 packed h0 every launch (ws re-poisoned to
// 0xAA before each timed call; 0xAAAAAAAA never equals a valid tag < 513, so
// parity buffer 1 needs no init).
__global__ __launch_bounds__(256) void lstm_prep(const float* __restrict__ h0,
                                                 unsigned long long* __restrict__ hbuf) {
  int g = blockIdx.x * 256 + threadIdx.x;   // grid 128 -> g in [0, 32768)
  unsigned pa = (unsigned)__builtin_bit_cast(unsigned short, (__bf16)h0[2 * g]);
  unsigned pb = (unsigned)__builtin_bit_cast(unsigned short, (__bf16)h0[2 * g + 1]);
  hbuf[g] = (unsigned long long)(pa | (pb << 16));   // tag 0 in high 32 bits
}

// Persistent LSTM. blockIdx.x = row-group r (16 batch rows), blockIdx.y =
// col-block cb (16 hidden cols of each of 4 gates). 256 blocks, 1/CU.
//
// Sync protocol (fence-free, placement-independent): h is exchanged as
// 64-bit relaxed agent-scope atomics packing (tag=step)<<32 | bf16-pair.
// The store IS the arrival signal; the consumer polls its own data slice
// until tags match — barrier and data movement share one L3 round trip.
// Parity double-buffering makes tag overwrite ABA-safe (slot with tag k is
// only rewritten with tag k+2, which requires every sibling to have
// consumed tag k — induction over the row-group sync domain).
__global__ __launch_bounds__(256) void lstm_main(
    const float* __restrict__ x,
    const float* __restrict__ c0,
    const float* __restrict__ Wf, const float* __restrict__ bf_,
    const float* __restrict__ Wi, const float* __restrict__ bi_,
    const float* __restrict__ Wc, const float* __restrict__ bc_,
    const float* __restrict__ Wo, const float* __restrict__ bo_,
    float* __restrict__ out,
    unsigned long long* __restrict__ hbuf)   // [2][NB][NH/2] tagged h pairs
{
  const int r    = blockIdx.x;   // row-group 0..15
  const int cb   = blockIdx.y;   // col-block 0..15
  const int tid  = threadIdx.x;
  const int w    = tid >> 6;     // wave id == gate id (f, i, c~, o)
  const int lane = tid & 63;
  const int l15  = lane & 15;
  const int kg   = lane >> 4;    // k-group 0..3 within MFMA fragment

  __shared__ __align__(16) unsigned char Ash[16 * KD * 2];  // 16 x 512 bf16, XOR-swizzled
  __shared__ float zbuf[4][16][17];                         // gate pre-activations

  const int j0    = cb * 16;
  const int brow0 = r * 16;

  // ---- B fragments: this wave's gate weights resident in VGPRs (64/lane) ----
  const float* Wg = (w == 0) ? Wf : (w == 1) ? Wi : (w == 2) ? Wc : Wo;
  bf16x8 bfrag[16];
  {
    const float* wp = Wg + (size_t)(j0 + l15) * KD + kg * 8;
#pragma unroll
    for (int s = 0; s < 16; ++s) {
      float4 lo = *(const float4*)(wp + s * 32);
      float4 hi = *(const float4*)(wp + s * 32 + 4);
      bf16x8 v;
      v[0] = (__bf16)lo.x; v[1] = (__bf16)lo.y; v[2] = (__bf16)lo.z; v[3] = (__bf16)lo.w;
      v[4] = (__bf16)hi.x; v[5] = (__bf16)hi.y; v[6] = (__bf16)hi.z; v[7] = (__bf16)hi.w;
      bfrag[s] = v;
    }
  }

  // ---- epilogue mapping: one thread per (row, col) of the 16x16 tile ----
  const int erow = tid >> 4, ecol = tid & 15;
  const int brow = brow0 + erow;
  const int jcol = j0 + ecol;
  const float biasf = bf_[jcol], biasi = bi_[jcol], biasc = bc_[jcol], biaso = bo_[jcol];
  float cst   = c0[brow * NH + jcol];
  float hlast = 0.f;

  const int swz  = (erow & 7) << 4;
  const int base = erow * 1024;

  // x_0 prefetch
  float4 xr0, xr1, xr2, xr3;
  {
    const float* xp = x + ((size_t)brow * 256 + ecol * 16);
    xr0 = ((const float4*)xp)[0]; xr1 = ((const float4*)xp)[1];
    xr2 = ((const float4*)xp)[2]; xr3 = ((const float4*)xp)[3];
  }

  for (int t = 0; t < LSEQ; ++t) {
    // 1) stage x_t (already in regs) into LDS k-region 256..511
    {
      bf16x8 p0, p1;
      p0[0] = (__bf16)xr0.x; p0[1] = (__bf16)xr0.y; p0[2] = (__bf16)xr0.z; p0[3] = (__bf16)xr0.w;
      p0[4] = (__bf16)xr1.x; p0[5] = (__bf16)xr1.y; p0[6] = (__bf16)xr1.z; p0[7] = (__bf16)xr1.w;
      p1[0] = (__bf16)xr2.x; p1[1] = (__bf16)xr2.y; p1[2] = (__bf16)xr2.z; p1[3] = (__bf16)xr2.w;
      p1[4] = (__bf16)xr3.x; p1[5] = (__bf16)xr3.y; p1[6] = (__bf16)xr3.z; p1[7] = (__bf16)xr3.w;
      *(uint4*)&Ash[(base + (256 + ecol * 16) * 2) ^ swz]     = __builtin_bit_cast(uint4, p0);
      *(uint4*)&Ash[(base + (256 + ecol * 16 + 8) * 2) ^ swz] = __builtin_bit_cast(uint4, p1);
    }
    // 2) issue x_{t+1} prefetch (hides under poll + MFMAs)
    {
      int tn = (t + 1 < LSEQ) ? t + 1 : t;
      const float* xp = x + ((size_t)tn * NB * 256 + (size_t)brow * 256 + ecol * 16);
      xr0 = ((const float4*)xp)[0]; xr1 = ((const float4*)xp)[1];
      xr2 = ((const float4*)xp)[2]; xr3 = ((const float4*)xp)[3];
    }
    __syncthreads();  // sync1: x staged

    // 3) x-half MFMAs (k = 256..511) — independent of h_t
    f32x4 acc = {0.f, 0.f, 0.f, 0.f};
#pragma unroll
    for (int s = 8; s < 16; ++s) {
      int ab = ((l15 * 1024) + (s * 32 + kg * 8) * 2) ^ ((l15 & 7) << 4);
      bf16x8 a = *(const bf16x8*)&Ash[ab];
      acc = __builtin_amdgcn_mfma_f32_16x16x32_bf16(a, bfrag[s], acc, 0, 0, 0);
    }

    // 4) poll h_t: thread owns row brow, u64 slots {i*16 + ecol}. The
    //    successful iteration's registers already hold the data.
    const unsigned long long* hp =
        hbuf + (size_t)(t & 1) * HBUF_U64 + (size_t)brow * HROW_U64;
    unsigned long long hv[8];
    while (1) {
      bool ok = true;
#pragma unroll
      for (int i = 0; i < 8; ++i) {
        hv[i] = __hip_atomic_load(&hp[i * 16 + ecol], __ATOMIC_RELAXED,
                                  __HIP_MEMORY_SCOPE_AGENT);
        ok &= ((unsigned)(hv[i] >> 32) == (unsigned)t);
      }
      if (ok) break;
    }

    // 5) stage h into LDS k-region 0..255 (low 32 bits = bf16 pair)
#pragma unroll
    for (int i = 0; i < 8; ++i)
      *(unsigned*)&Ash[(base + (i * 16 + ecol) * 4) ^ swz] = (unsigned)hv[i];
    __syncthreads();  // sync2: h staged

    // 6) h-half MFMAs (k = 0..255)
#pragma unroll
    for (int s = 0; s < 8; ++s) {
      int ab = ((l15 * 1024) + (s * 32 + kg * 8) * 2) ^ ((l15 & 7) << 4);
      bf16x8 a = *(const bf16x8*)&Ash[ab];
      acc = __builtin_amdgcn_mfma_f32_16x16x32_bf16(a, bfrag[s], acc, 0, 0, 0);
    }
    // C/D layout: col = lane&15, row = (lane>>4)*4 + reg  [m89-verified]
#pragma unroll
    for (int v4i = 0; v4i < 4; ++v4i) zbuf[w][kg * 4 + v4i][l15] = acc[v4i];
    __syncthreads();  // sync3: zbuf complete

    // 7) elementwise gate math; one thread per (row, col)
    float zf = zbuf[0][erow][ecol] + biasf;
    float zi = zbuf[1][erow][ecol] + biasi;
    float zc = zbuf[2][erow][ecol] + biasc;
    float zo = zbuf[3][erow][ecol] + biaso;
    float fg    = 1.f / (1.f + __expf(-zf));
    float ig    = 1.f / (1.f + __expf(-zi));
    float ccand = 1.f - 2.f / (__expf(2.f * zc) + 1.f);   // tanh
    float og    = 1.f / (1.f + __expf(-zo));
    cst   = fg * cst + ig * ccand;
    float tc = 1.f - 2.f / (__expf(2.f * cst) + 1.f);     // tanh
    hlast = og * tc;

    // 8) publish h_{t+1}: ONE tagged 64-bit store per thread-pair —
    //    fire-and-forget, no drain, no counter.
    unsigned mybits = (unsigned)__builtin_bit_cast(unsigned short, (__bf16)hlast);
    unsigned nbbits = __shfl_down(mybits, 1);
    if ((ecol & 1) == 0) {
      unsigned long long pkt =
          ((unsigned long long)(unsigned)(t + 1) << 32) |
          (unsigned long long)(mybits | (nbbits << 16));
      __hip_atomic_store(&hbuf[(size_t)((t + 1) & 1) * HBUF_U64 +
                               (size_t)brow * HROW_U64 + cb * 8 + (ecol >> 1)],
                         pkt, __ATOMIC_RELAXED, __HIP_MEMORY_SCOPE_AGENT);
    }

    // 9) hAll output (off critical path, plain cached store)
    out[(size_t)t * NB * NH + brow * NH + jcol] = hlast;
  }

  // finals: h_final, c_final
  out[(size_t)LSEQ * NB * NH + brow * NH + jcol]           = hlast;
  out[(size_t)LSEQ * NB * NH + NB * NH + brow * NH + jcol] = cst;
}

extern "C" void kernel_launch(void* const* d_in, const int* in_sizes, int n_in,
                              void* d_out, int out_size, void* d_ws, size_t ws_size,
                              hipStream_t stream) {
  const float* x  = (const float*)d_in[0];
  const float* h0 = (const float*)d_in[1];
  const float* c0 = (const float*)d_in[2];
  const float* Wf = (const float*)d_in[3];
  const float* bf = (const float*)d_in[4];
  const float* Wi = (const float*)d_in[5];
  const float* bi = (const float*)d_in[6];
  const float* Wc = (const float*)d_in[7];
  const float* bc = (const float*)d_in[8];
  const float* Wo = (const float*)d_in[9];
  const float* bo = (const float*)d_in[10];
  float* out = (float*)d_out;

  unsigned long long* hbuf = (unsigned long long*)d_ws;   // 2 x 256 KB

  lstm_prep<<<128, 256, 0, stream>>>(h0, hbuf);
  lstm_main<<<dim3(16, 16), 256, 0, stream>>>(x, c0, Wf, bf, Wi, bi, Wc, bc,
                                              Wo, bo, out, hbuf);
}